// Round 7
// baseline (170.269 us; speedup 1.0000x reference)
//
#include <hip/hip_runtime.h>

#define CIN   128
#define HH    224
#define WW    224
#define COUT  256
#define HO    222
#define WO    222

typedef unsigned short u16;
typedef unsigned int   u32;
typedef __bf16  bf16x8 __attribute__((ext_vector_type(8)));
typedef float   f32x4  __attribute__((ext_vector_type(4)));

__device__ __forceinline__ u16 f2bf(float f) {
  union { float f; u32 u; } v; v.f = f;
  u32 u = v.u;
  return (u16)((u + 0x7FFFu + ((u >> 16) & 1u)) >> 16);  // RNE
}

// ---------------- merged pre-pass (448 x-blocks + 144 w-blocks) ----------------
// No swizzle anymore: conv reads fragments straight from global (no LDS banks).
// x-pack: xp [h(224)][w(224)][c(128)] bf16 (K-major per pixel, 256B records).
//   XCD-aligned with consumer band: row h packed on XCD h/28 (round-robin
//   dispatch => xcd = bx&7), so conv's reads hit the L2 the pack left dirty.
// w-pack: wp [mt(2)][kh(3)][ch(2)][kw(3)][mr(128)][c8(8)][e(8)] bf16.
__global__ void prep(const float* __restrict__ x, const float* __restrict__ w,
                     u16* __restrict__ xp, u16* __restrict__ wp) {
  const int t = threadIdx.x;
  if (blockIdx.x < 448) {
    const int xcd = blockIdx.x & 7;
    const int q   = blockIdx.x >> 3;          // 0..55
    const int h   = xcd * 28 + (q >> 1);      // 0..223, owned by consumer XCD
    const int wb  = q & 1;                    // w-half
    __shared__ u16 tile[128][116];            // 29.7 KB
#pragma unroll
    for (int i = 0; i < 14; ++i) {            // 128 c-rows * 28 float4 = 3584 units
      int idx = i * 256 + t;
      int c   = idx / 28;
      int wq  = idx % 28;
      float4 v = *(const float4*)(&x[(size_t)c * (HH * WW) + h * WW + wb * 112 + wq * 4]);
      uint2 p;
      p.x = (u32)f2bf(v.x) | ((u32)f2bf(v.y) << 16);
      p.y = (u32)f2bf(v.z) | ((u32)f2bf(v.w) << 16);
      *(uint2*)(&tile[c][wq * 4]) = p;
    }
    __syncthreads();
#pragma unroll
    for (int i = 0; i < 7; ++i) {             // 112 w * 16 c-blocks = 1792
      int idx  = i * 256 + t;
      int wl   = idx >> 4;                    // 0..111
      int jc   = idx & 15;
      int ww   = wb * 112 + wl;
      uint4 v;
      v.x = (u32)tile[jc * 8 + 0][wl] | ((u32)tile[jc * 8 + 1][wl] << 16);
      v.y = (u32)tile[jc * 8 + 2][wl] | ((u32)tile[jc * 8 + 3][wl] << 16);
      v.z = (u32)tile[jc * 8 + 4][wl] | ((u32)tile[jc * 8 + 5][wl] << 16);
      v.w = (u32)tile[jc * 8 + 6][wl] | ((u32)tile[jc * 8 + 7][wl] << 16);
      *(uint4*)(&xp[((size_t)h * WW + ww) * 128 + jc * 8]) = v;
    }
  } else {
    int u    = (blockIdx.x - 448) * 256 + t;  // 0..36863 (16B blocks of wp)
    int jc   = u & 7;
    int mr   = (u >> 3) & 127;
    int rest = u >> 10;                       // ((mt*3+kh)*2+ch)*3+kw
    int kw   = rest % 3;
    int q    = rest / 3;
    int ch   = q & 1;
    int r    = q >> 1;
    int kh   = r % 3;
    int mt   = r / 3;
    int oc   = mt * 128 + mr;
    int cb   = ch * 64 + jc * 8;
    u16 o[8];
#pragma unroll
    for (int e = 0; e < 8; ++e)
      o[e] = f2bf(w[((size_t)(oc * CIN + cb + e) * 3 + kh) * 3 + kw]);
    uint4 v;
    v.x = (u32)o[0] | ((u32)o[1] << 16);
    v.y = (u32)o[2] | ((u32)o[3] << 16);
    v.z = (u32)o[4] | ((u32)o[5] << 16);
    v.w = (u32)o[6] | ((u32)o[7] << 16);
    *(uint4*)(&wp[(size_t)u * 8]) = v;
  }
}

// ---------------- main: LDS-free, barrier-free implicit-GEMM conv ----------------
// One wave per block (64 threads), grid 1792 = 8 xcd * 224 r. bx&7 = xcd under
// round-robin dispatch; XCD k owns rows k*28..k*28+27 (its L2 holds those xp
// rows dirty from prep). r = bx>>3: oh = xcd*28 + (r>>3); sub = r&7 ->
// (mt, wm, wn). Wave tile 64x112 = 4x7 frags of 16x16x32, acc 112 VGPR.
// A and B fragments are loaded DIRECTLY global->VGPR (wp ~0.6MB L2-resident;
// xp rows band-resident): per 16-lane group each load is a 64B-contiguous
// segment -> clean coalescing. No __shared__, no __syncthreads, no vmcnt(0)
// phase coupling: every wave is an independent load->MFMA stream, ~7 waves/CU
// balanced (vs 1.73 4-wave blocks before: the R1..R5-invariant 690 TF was the
// block-quantum imbalance + barrier phase coupling, not staging efficiency).
__global__ __launch_bounds__(64, 2) void conv_mfma(const u16* __restrict__ wp,
                                                   const u16* __restrict__ xp,
                                                   float* __restrict__ out) {
  const int lane = threadIdx.x;
  const int quad = lane >> 4;
  const int lr   = lane & 15;

  const int bx  = blockIdx.x;
  const int xcd = bx & 7;
  const int r   = bx >> 3;                // 0..223
  const int oh  = xcd * 28 + (r >> 3);    // 0..223
  if (oh >= HO) return;                   // 16 idle blocks (xcd 7)
  const int sub = r & 7;
  const int mt  = sub & 1;
  const int wm  = (sub >> 1) & 1;
  const int wn  = sub >> 2;

  f32x4 acc[4][7];
#pragma unroll
  for (int i = 0; i < 4; ++i)
#pragma unroll
    for (int j = 0; j < 7; ++j) acc[i][j] = {0.f, 0.f, 0.f, 0.f};

  for (int kh = 0; kh < 3; ++kh) {
    // per-lane bases: A row mr = wm*64 + i*16 + lr; B pixel = wn*112 + lr + kw + j*16
    const u16* Arow = wp + (size_t)(mt * 3 + kh) * 2 * 24576 + (wm * 64 + lr) * 64;
    const u16* Brow = xp + (size_t)(oh + kh) * (WW * 128) + (wn * 112 + lr) * 128;

#pragma unroll
    for (int kw = 0; kw < 3; ++kw) {
#pragma unroll
      for (int ks = 0; ks < 4; ++ks) {    // K=32 window; ch = ks>>1
        const u16* Ak = Arow + (ks >> 1) * 24576 + kw * 8192 + ((ks & 1) * 4 + quad) * 8;
        const u16* Bk = Brow + kw * 128 + (ks * 4 + quad) * 8;
        bf16x8 af[4], bg[7];
#pragma unroll
        for (int i = 0; i < 4; ++i)
          af[i] = *reinterpret_cast<const bf16x8*>(Ak + i * 1024);
#pragma unroll
        for (int j = 0; j < 7; ++j)
          bg[j] = *reinterpret_cast<const bf16x8*>(Bk + j * 2048);
#pragma unroll
        for (int i = 0; i < 4; ++i)
#pragma unroll
          for (int j = 0; j < 7; ++j)
            acc[i][j] = __builtin_amdgcn_mfma_f32_16x16x32_bf16(af[i], bg[j], acc[i][j], 0, 0, 0);
      }
    }
  }

  // epilogue: C/D map col=lane&15, row=quad*4+reg (m89/m91); mask cols 222/223.
  // (Cols 222/223 accumulated garbage from <=528B of reads past row end — lands
  //  in ws padding, never stored.)
  const int mb = mt * 128 + wm * 64;
#pragma unroll
  for (int i = 0; i < 4; ++i) {
#pragma unroll
    for (int j = 0; j < 7; ++j) {
      const int col = wn * 112 + j * 16 + lr;
      if (col < WO) {
        float* op = out + (size_t)(mb + i * 16 + quad * 4) * (HO * WO) +
                    (size_t)oh * WO + col;
#pragma unroll
        for (int r4 = 0; r4 < 4; ++r4)
          op[(size_t)r4 * (HO * WO)] = acc[i][j][r4];
      }
    }
  }
}

// ---------------- fallback (ws too small): naive fp32 direct conv ----------------
__global__ void conv_naive(const float* __restrict__ x, const float* __restrict__ w,
                           float* __restrict__ out) {
  int idx = blockIdx.x * 256 + threadIdx.x;
  if (idx >= COUT * HO * WO) return;
  int ow  = idx % WO;
  int tmp = idx / WO;
  int oh  = tmp % HO;
  int oc  = tmp / HO;
  float s = 0.f;
  for (int c = 0; c < CIN; ++c)
    for (int kh = 0; kh < 3; ++kh) {
      const float* xr = &x[(size_t)(c * HH + oh + kh) * WW + ow];
      const float* wr = &w[((size_t)(oc * CIN + c) * 3 + kh) * 3];
      s += xr[0] * wr[0] + xr[1] * wr[1] + xr[2] * wr[2];
    }
  out[idx] = s;
}

extern "C" void kernel_launch(void* const* d_in, const int* in_sizes, int n_in,
                              void* d_out, int out_size, void* d_ws, size_t ws_size,
                              hipStream_t stream) {
  const float* x    = (const float*)d_in[0];
  const float* kern = (const float*)d_in[1];
  float* out        = (float*)d_out;

  const size_t WP_BYTES = (size_t)36864 * 16;            // 589,824
  const size_t XP_BYTES = (size_t)HH * WW * 128 * 2;     // 12,845,056

  if (ws_size >= WP_BYTES + XP_BYTES + 1024) {           // +pad for masked-col overread
    u16* wp = (u16*)d_ws;
    u16* xp = (u16*)((char*)d_ws + WP_BYTES);
    hipLaunchKernelGGL(prep, dim3(592), dim3(256), 0, stream, x, kern, xp, wp);
    hipLaunchKernelGGL(conv_mfma, dim3(1792), dim3(64), 0, stream, wp, xp, out);
  } else {
    int total = COUT * HO * WO;
    hipLaunchKernelGGL(conv_naive, dim3((total + 255) / 256), dim3(256), 0, stream,
                       x, kern, out);
  }
}